// Round 12
// baseline (167.939 us; speedup 1.0000x reference)
//
#include <hip/hip_runtime.h>
#include <stdint.h>

#define D_MODEL 1024
#define NH      16
#define DKH     64
#define SEQLEN  2048
#define BATCH   2
#define KDIM    1024   // inner dim of all projections

typedef __attribute__((ext_vector_type(8))) short          short8;   // 8 bf16 (4 VGPRs)
typedef __attribute__((ext_vector_type(4))) short          bf16x4;   // 4 bf16 (2 VGPRs)
typedef __attribute__((ext_vector_type(8))) unsigned short ushort8;
typedef __attribute__((ext_vector_type(4))) unsigned short usht4;    // 'ushort4' is taken by HIP
typedef __attribute__((ext_vector_type(4))) float          f32x4;

// exp2(q·k) where q pre-scaled by 0.125*log2(e) == exp(q·k/8)
#define QSCALE 0.18033688011112042f

// ---------- helpers ----------
__device__ __forceinline__ unsigned short f2bf(float f) {
    union { float f; unsigned u; } v; v.f = f;
    unsigned u = v.u;
    unsigned r = (u + 0x7FFFu + ((u >> 16) & 1u)) >> 16;   // RNE
    return (unsigned short)r;
}
__device__ __forceinline__ unsigned fbits(float f) {
    union { float f; unsigned u; } v; v.f = f; return v.u;
}

__device__ __forceinline__ void gload_lds16(const unsigned short* g, unsigned short* l) {
    __builtin_amdgcn_global_load_lds(
        (__attribute__((address_space(1))) void*)(g),
        (__attribute__((address_space(3))) void*)(l), 16, 0, 0);
}

// ---------- kernel 0: fp32 -> bf16 convert (5 tensors) + RoPE cos/sin table ----------
// COMPACT 1D grid (4352 blocks): X 2048 | Wq/Wk/Wv/Wo 512 each | tbl 256.
__global__ void cvt_all(const float* __restrict__ X,  const float* __restrict__ Wq,
                        const float* __restrict__ Wk, const float* __restrict__ Wv,
                        const float* __restrict__ Wo, const int* __restrict__ pos,
                        unsigned short* __restrict__ Xb,  unsigned short* __restrict__ Wqb,
                        unsigned short* __restrict__ Wkb, unsigned short* __restrict__ Wvb,
                        unsigned short* __restrict__ Wob, float2* __restrict__ tbl) {
    const int bid = blockIdx.x;
    if (bid >= 4096) {
        int i = (bid - 4096) * 256 + threadIdx.x;   // tbl[s][j], 2048*32 = 65536 exact
        int s = i >> 5, j = i & 31;
        float freq = expf(-((float)(2 * j) * (1.0f / 64.0f)) * 9.210340371976184f);
        float ang = (float)pos[s] * freq;
        float sn, cn;
        sincosf(ang, &sn, &cn);
        tbl[i] = make_float2(cn, sn);
        return;
    }
    const float* src; unsigned short* dst; int local;
    if (bid < 2048) { src = X; dst = Xb; local = bid; }
    else {
        int wb = bid - 2048;            // 0..2047
        int wz = wb >> 9;               // 0..3
        local  = wb & 511;
        if (wz == 0)      { src = Wq; dst = Wqb; }
        else if (wz == 1) { src = Wk; dst = Wkb; }
        else if (wz == 2) { src = Wv; dst = Wvb; }
        else              { src = Wo; dst = Wob; }
    }
    int i = (local * 256 + threadIdx.x) * 8;        // exact coverage, no bounds check
    float4 a = *(const float4*)(src + i);
    float4 b = *(const float4*)(src + i + 4);
    ushort8 o;
    o[0] = f2bf(a.x); o[1] = f2bf(a.y); o[2] = f2bf(a.z); o[3] = f2bf(a.w);
    o[4] = f2bf(b.x); o[5] = f2bf(b.y); o[6] = f2bf(b.z); o[7] = f2bf(b.w);
    *(ushort8*)(dst + i) = o;
}

// ---------- GEMM core A (qkv): C[128x128] = A * W^T, K=1024, BK=32, DOUBLE-BUFFERED ----
// NEW (R12): BK=32 halves each buffer, so full double-buffering costs the SAME 41 KB
// as the old single-buffer BK=64 -> 3 blocks/CU KEPT (R4's failure avoided), while
// stage(t+1) now issues BEFORE compute(t): the barrier's vmcnt(0) drain lands after
// ~176 cyc of ds_read+MFMA cover instead of immediately after issue. Barrier count
// unchanged (32x1 vs 16x2). Waves/reads-per-MFMA/acc all unchanged (R6/R10 avoided).
// Swizzle: BK=32 rows are 64B -> only a 2-bit XOR fits: LDS slot s of row r holds
// global k-group s ^ (r&3). Frag reads become 4-way bank-conflicted; per m252 the
// 2-phase critical path hides read conflicts (T2 null at 2ph) -> counter up, time not.
__device__ __forceinline__ void gemm_core_128(
    const unsigned short* __restrict__ A, const unsigned short* __restrict__ W,
    unsigned short* a_lds, unsigned short* b_lds,   // each 2 x 4096 ushorts (dbuf)
    int m0, int n0, f32x4 acc[4][4])
{
    const int tid  = threadIdx.x;
    const int lane = tid & 63;
    const int w    = tid >> 6;
    const int quad = lane >> 4;
    const int l16  = lane & 15;
    const int wm   = w & 1, wn = w >> 1;

    const int row_in = lane >> 2;                 // 0..15 row within 16-row chunk
    const int cg     = ((lane & 3) ^ (row_in & 3)) * 8; // xor-swizzled k-group (elems)

    #pragma unroll
    for (int mi = 0; mi < 4; mi++)
        #pragma unroll
        for (int ni = 0; ni < 4; ni++) {
            f32x4 z = {0.f, 0.f, 0.f, 0.f};
            acc[mi][ni] = z;
        }

    const int x3 = l16 & 3;                       // = row&3 for all frag rows

    // prologue: stage k=0 into buffer 0 (2 chunks of 16 rows x 32 k per matrix per wave)
    #pragma unroll
    for (int j = 0; j < 2; ++j) {
        int c = w * 2 + j;                        // chunk: 16 rows x 32 k (1KB)
        gload_lds16(A + (size_t)(m0 + c * 16 + row_in) * KDIM + cg, &a_lds[c * 512]);
        gload_lds16(W + (size_t)(n0 + c * 16 + row_in) * KDIM + cg, &b_lds[c * 512]);
    }
    __syncthreads();

    int cur = 0;
    for (int kk = 0; kk < KDIM; kk += 32) {
        // stage NEXT K-step into the idle buffer; overlaps ds_read+MFMA below
        if (kk + 32 < KDIM) {
            const int nxt = cur ^ 1;
            #pragma unroll
            for (int j = 0; j < 2; ++j) {
                int c = w * 2 + j;
                gload_lds16(A + (size_t)(m0 + c * 16 + row_in) * KDIM + kk + 32 + cg,
                            &a_lds[nxt * 4096 + c * 512]);
                gload_lds16(W + (size_t)(n0 + c * 16 + row_in) * KDIM + kk + 32 + cg,
                            &b_lds[nxt * 4096 + c * 512]);
            }
        }

        const unsigned short* al = &a_lds[cur * 4096];
        const unsigned short* bl = &b_lds[cur * 4096];
        const int g = (quad ^ x3) * 8;            // de-swizzled slot for this quad's k-group
        short8 af[4], bf[4];
        #pragma unroll
        for (int i = 0; i < 4; i++) {
            af[i] = *(const short8*)&al[(wm * 64 + i * 16 + l16) * 32 + g];
            bf[i] = *(const short8*)&bl[(wn * 64 + i * 16 + l16) * 32 + g];
        }
        #pragma unroll
        for (int mi = 0; mi < 4; mi++)
            #pragma unroll
            for (int ni = 0; ni < 4; ni++)
                acc[mi][ni] = __builtin_amdgcn_mfma_f32_16x16x32_bf16(af[mi], bf[ni], acc[mi][ni], 0, 0, 0);

        // one barrier per K-step: vmcnt(0) -> next buffer landed; cur readers done
        __syncthreads();
        cur ^= 1;
    }
}

// ---------- GEMM core B (out): C[128x64] = A * W^T, DOUBLE-BUFFERED BK=64 ----------
// gemm_out's grid gives 2 blocks/CU (512 blocks); LDS 48KB keeps both resident.
__device__ __forceinline__ void gemm_core_128x64_db(
    const unsigned short* __restrict__ A, const unsigned short* __restrict__ W,
    unsigned short* a_lds, unsigned short* b_lds,   // a: 2*8192, b: 2*4096 ushorts
    int m0, int n0, f32x4 acc[4][2])
{
    const int tid  = threadIdx.x;
    const int lane = tid & 63;
    const int w    = tid >> 6;
    const int quad = lane >> 4;
    const int l16  = lane & 15;
    const int wm   = w & 1, wn = w >> 1;          // 2(m) x 2(n) waves, 64x32 each

    const int row_in = lane >> 3;
    const int cg     = ((lane & 7) ^ row_in) * 8;

    #pragma unroll
    for (int mi = 0; mi < 4; mi++)
        #pragma unroll
        for (int ni = 0; ni < 2; ni++) {
            f32x4 z = {0.f, 0.f, 0.f, 0.f};
            acc[mi][ni] = z;
        }

    const int x7 = l16 & 7;

    // prologue: stage k=0 into buffer 0
    #pragma unroll
    for (int j = 0; j < 4; ++j) {
        int c = w * 4 + j;                        // A: 16 chunks of 8 rows
        gload_lds16(A + (size_t)(m0 + c * 8 + row_in) * KDIM + cg, &a_lds[c * 512]);
    }
    #pragma unroll
    for (int j = 0; j < 2; ++j) {
        int c = w * 2 + j;                        // B: 8 chunks of 8 rows
        gload_lds16(W + (size_t)(n0 + c * 8 + row_in) * KDIM + cg, &b_lds[c * 512]);
    }
    __syncthreads();

    int cur = 0;
    for (int kk = 0; kk < KDIM; kk += 64) {
        if (kk + 64 < KDIM) {
            const int nxt = cur ^ 1;
            #pragma unroll
            for (int j = 0; j < 4; ++j) {
                int c = w * 4 + j;
                gload_lds16(A + (size_t)(m0 + c * 8 + row_in) * KDIM + kk + 64 + cg,
                            &a_lds[nxt * 8192 + c * 512]);
            }
            #pragma unroll
            for (int j = 0; j < 2; ++j) {
                int c = w * 2 + j;
                gload_lds16(W + (size_t)(n0 + c * 8 + row_in) * KDIM + kk + 64 + cg,
                            &b_lds[nxt * 4096 + c * 512]);
            }
        }

        const unsigned short* al = &a_lds[cur * 8192];
        const unsigned short* bl = &b_lds[cur * 4096];
        short8 af[2][4], bf[2][2];
        #pragma unroll
        for (int kk2 = 0; kk2 < 2; kk2++) {
            #pragma unroll
            for (int i = 0; i < 4; i++) {
                int g = (kk2 * 4 + quad) ^ x7;
                af[kk2][i] = *(const short8*)&al[(wm * 64 + i * 16 + l16) * 64 + g * 8];
            }
            #pragma unroll
            for (int i = 0; i < 2; i++) {
                int g = (kk2 * 4 + quad) ^ x7;
                bf[kk2][i] = *(const short8*)&bl[(wn * 32 + i * 16 + l16) * 64 + g * 8];
            }
        }
        #pragma unroll
        for (int kk2 = 0; kk2 < 2; kk2++)
            #pragma unroll
            for (int mi = 0; mi < 4; mi++)
                #pragma unroll
                for (int ni = 0; ni < 2; ni++)
                    acc[mi][ni] = __builtin_amdgcn_mfma_f32_16x16x32_bf16(af[kk2][mi], bf[kk2][ni], acc[mi][ni], 0, 0, 0);

        __syncthreads();       // vmcnt(0): next buffer landed; cur readers done
        cur ^= 1;
    }
}

// ---------- kernel 1: QKV projection + fused RoPE (Q,K) + V^T transpose-store ----------
__global__ __launch_bounds__(256, 2)
void gemm_qkv(const unsigned short* __restrict__ X,
              const unsigned short* __restrict__ Wq,
              const unsigned short* __restrict__ Wk,
              const unsigned short* __restrict__ Wv,
              const float2* __restrict__ tbl,
              unsigned short* __restrict__ q_ws,
              unsigned short* __restrict__ k_ws,
              unsigned short* __restrict__ v_ws)
{
    __shared__ __align__(16) unsigned short a_lds[2 * 128 * 32];   // 16 KB (dbuf)
    __shared__ __align__(16) unsigned short b_lds[2 * 128 * 32];   // 16 KB (dbuf)
    __shared__ __align__(16) unsigned short t_lds[32 * 136];       // V transpose staging

    const int z = blockIdx.z;
    const unsigned short* W = (z == 0) ? Wq : ((z == 1) ? Wk : Wv);
    const int m0 = blockIdx.x * 128, n0 = blockIdx.y * 128;

    f32x4 acc[4][4];
    gemm_core_128(X, W, a_lds, b_lds, m0, n0, acc);

    const int tid  = threadIdx.x;
    const int lane = tid & 63;
    const int w    = tid >> 6;
    const int quad = lane >> 4;
    const int l16  = lane & 15;
    const int wm   = w & 1, wn = w >> 1;

    if (z == 2) {
        // ---- V: transpose 128x128 tile through LDS, store [bh][d][s] coalesced ----
        const int bx = m0 >> 11;                 // batch
        const int c_local_w = wn * 16 + l16;     // writer column slot 0..31
        const int rd_c = tid >> 3;               // reader column slot 0..31
        const int rd_s = (tid & 7) * 16;         // reader s-offset
        #pragma unroll
        for (int ni = 0; ni < 4; ni++) {
            __syncthreads();                     // prior pass reads done
            #pragma unroll
            for (int mi = 0; mi < 4; mi++) {
                usht4 v4;
                #pragma unroll
                for (int r = 0; r < 4; r++) v4[r] = f2bf(acc[mi][ni][r]);
                *(usht4*)&t_lds[c_local_w * 136 + wm * 64 + mi * 16 + quad * 4] = v4;
            }
            __syncthreads();
            int col = n0 + (rd_c >> 4) * 64 + ni * 16 + (rd_c & 15);
            int h = col >> 6, d = col & 63;
            size_t base = (size_t)(bx * NH + h) * DKH * SEQLEN + (size_t)d * SEQLEN
                        + (m0 & 2047) + rd_s;
            ushort8 x0 = *(ushort8*)&t_lds[rd_c * 136 + rd_s];
            ushort8 x1 = *(ushort8*)&t_lds[rd_c * 136 + rd_s + 8];
            *(ushort8*)&v_ws[base]     = x0;
            *(ushort8*)&v_ws[base + 8] = x1;
        }
    } else {
        // ---- Q/K: fused RoPE on fp32 acc, then round once ----
        unsigned short* dst = (z == 0) ? q_ws : k_ws;
        const float sc = (z == 0) ? QSCALE : 1.0f;
        #pragma unroll
        for (int mi = 0; mi < 4; mi++)
            #pragma unroll
            for (int ni = 0; ni < 4; ni++)
                #pragma unroll
                for (int r = 0; r < 4; r++) {
                    int row = m0 + wm * 64 + mi * 16 + quad * 4 + r;
                    int col = n0 + wn * 64 + ni * 16 + l16;
                    int b = row >> 11, s = row & 2047;
                    int h = col >> 6,  d = col & 63;
                    float val = acc[mi][ni][r];
                    float other = __shfl_xor(val, 1);     // RoPE partner: col^1 == lane^1
                    float2 cs = tbl[s * 32 + (d >> 1)];
                    float rv = (d & 1) ? (other * cs.y + val * cs.x)
                                       : (val * cs.x - other * cs.y);
                    dst[(size_t)(b * NH + h) * SEQLEN * DKH + (size_t)s * DKH + d] =
                        f2bf(rv * sc);
                }
    }
}

// ---------- kernel 2: causal flash attention (S^T trick; 128q x 128k blocks) ----------
// grid (bh=32, y=16): qt = (y<8) ? y : 23-y -> CU-paired load balance, 2 resident
// blocks/CU. K/V LDS double-buffered (71.7 KB), ONE barrier per key-tile.
// PV uses mfma_f32_16x16x32_bf16 (K=32) via key-permuted V LDS layout (R9):
// within each 32-key group, key [sub][q2][r] stored at column [q2][sub][r], so a
// contiguous short8 at (grp*32+quad*8) is the K=32 A-operand, and B is the packed
// {s_even[0..3], s_odd[0..3]} bf16 fragment. S^T = K·Q^T; O^T in C-layout.
__global__ __launch_bounds__(512, 2)
void attn_kernel(const unsigned short* __restrict__ q_ws,
                 const unsigned short* __restrict__ k_ws,
                 const unsigned short* __restrict__ v_ws,
                 unsigned short* __restrict__ ao)
{
    // per buffer: k 128*72 (18432B) + v 64*136 (17408B) = 35840B; x2 = 71680B.
    // Reduction view (aliased over buf0): redO 8192 f32 (32KB) + redL 512 f32 (2KB).
    __shared__ __align__(16) unsigned short smem[2 * 17920];
    float* redO = (float*)smem;
    float* redL = redO + 8192;

    const int bh  = blockIdx.x;
    const int y   = blockIdx.y;         // 0..15
    const int qt2 = (y < 8) ? y : (23 - y);   // CU-pairing balance map
    const int tid = threadIdx.x, lane = tid & 63, w = tid >> 6;
    const int quad = lane >> 4, l16 = lane & 15;
    const int g   = w >> 2;             // key-half group (0: keys 0-63, 1: keys 64-127)
    const int w4  = w & 3;              // query strip owner within group
    const int nf0 = g * 4;

    const size_t kqbase = (size_t)bh * SEQLEN * DKH;
    const size_t vbase  = (size_t)bh * DKH * SEQLEN;
    const int b = bh >> 4, h = bh & 15;

    // staging (512 threads, 2 chunks each)
    const int krow = tid >> 3, kcol = (tid & 7) * 8;     // K: rows krow, krow+64
    const int vrow = tid >> 4;                           // V: rows vrow, vrow+32
    const int vt   = tid & 15;                           // global key group: keys vt*8..+7
    // permuted LDS column base for keys vt*8+e: e0..3 -> +0..3, e4..7 -> +8..11
    const int vcol0 = ((vt >> 2) * 32) + ((vt & 1) * 16) + (((vt >> 1) & 1) * 4);

    const int q0  = qt2 * 128;
    const int nt  = qt2 + 1;              // # of 128-key tiles
    const int qwbase = q0 + w4 * 32;      // this wave's 32 queries

    short8 aq[2][2];
    #pragma unroll
    for (int st = 0; st < 2; st++)
        #pragma unroll
        for (int kc2 = 0; kc2 < 2; kc2++)
            aq[st][kc2] = *(const short8*)(q_ws + kqbase +
                (size_t)(qwbase + st * 16 + l16) * DKH + kc2 * 32 + quad * 8);

    f32x4 o_acc[2][4];
    #pragma unroll
    for (int st = 0; st < 2; st++)
        #pragma unroll
        for (int df = 0; df < 4; df++) { f32x4 z = {0.f,0.f,0.f,0.f}; o_acc[st][df] = z; }
    float lsum[2] = {0.f, 0.f};

    // prologue: load + stage tile 0 into buffer 0
    ushort8 kreg[2], vreg[2];
    #pragma unroll
    for (int rr = 0; rr < 2; ++rr) {
        kreg[rr] = *(const ushort8*)(k_ws + kqbase + (size_t)(krow + rr * 64) * DKH + kcol);
        vreg[rr] = *(const ushort8*)(v_ws + vbase + (size_t)(vrow + rr * 32) * SEQLEN + vt * 8);
    }
    {
        unsigned short* k0 = smem;
        unsigned short* v0 = smem + 128 * 72;
        #pragma unroll
        for (int rr = 0; rr < 2; ++rr) {
            *(ushort8*)&k0[(krow + rr * 64) * 72 + kcol] = kreg[rr];
            usht4 lo, hi2;
            #pragma unroll
            for (int e = 0; e < 4; e++) { lo[e] = vreg[rr][e]; hi2[e] = vreg[rr][e + 4]; }
            *(usht4*)&v0[(vrow + rr * 32) * 136 + vcol0]     = lo;
            *(usht4*)&v0[(vrow + rr * 32) * 136 + vcol0 + 8] = hi2;
        }
    }
    __syncthreads();

    for (int t = 0; t < nt; ++t) {
        const int s0 = t * 128;
        unsigned short* kc = smem + (t & 1) * 17920;
        unsigned short* vc = kc + 128 * 72;

        if (t < nt - 1) {
            int s1 = s0 + 128;
            #pragma unroll
            for (int rr = 0; rr < 2; ++rr) {
                kreg[rr] = *(const ushort8*)(k_ws + kqbase + (size_t)(s1 + krow + rr * 64) * DKH + kcol);
                vreg[rr] = *(const ushort8*)(v_ws + vbase + (size_t)(vrow + rr * 32) * SEQLEN + s1 + vt * 8);
            }
        }

        const bool diag = (t == nt - 1);
        #pragma unroll
        for (int np = 0; np < 2; np++) {
            unsigned pku[2][4];                 // [st][4] packed bf16 P fragments
            #pragma unroll
            for (int sub = 0; sub < 2; sub++) {
                const int nf = nf0 + np * 2 + sub;
                short8 kf0 = *(const short8*)&kc[(nf * 16 + l16) * 72 + 0 * 32 + quad * 8];
                short8 kf1 = *(const short8*)&kc[(nf * 16 + l16) * 72 + 1 * 32 + quad * 8];
                #pragma unroll
                for (int st = 0; st < 2; st++) {
                    f32x4 s = {0.f,0.f,0.f,0.f};
                    s = __builtin_amdgcn_mfma_f32_16x16x32_bf16(kf0, aq[st][0], s, 0, 0, 0);
                    s = __builtin_amdgcn_mfma_f32_16x16x32_bf16(kf1, aq[st][1], s, 0, 0, 0);

                    if (diag) {
                        int qg = qwbase + st * 16 + l16;
                        int kg = s0 + nf * 16 + quad * 4;
                        #pragma unroll
                        for (int r = 0; r < 4; r++)
                            s[r] = (kg + r <= qg) ? __builtin_amdgcn_exp2f(s[r]) : 0.f;
                    } else {
                        #pragma unroll
                        for (int r = 0; r < 4; r++)
                            s[r] = __builtin_amdgcn_exp2f(s[r]);
                    }
                    lsum[st] += s[0] + s[1] + s[2] + s[3];
                    pku[st][sub * 2]     = __builtin_amdgcn_perm(fbits(s[1]), fbits(s[0]), 0x07060302u);
                    pku[st][sub * 2 + 1] = __builtin_amdgcn_perm(fbits(s[3]), fbits(s[2]), 0x07060302u);
                }
            }

            // V fragments for this 32-key group (permuted layout -> contiguous b128)
            short8 vf8[4];
            #pragma unroll
            for (int df = 0; df < 4; df++)
                vf8[df] = *(const short8*)&vc[(df * 16 + l16) * 136 + (g * 2 + np) * 32 + quad * 8];

            #pragma unroll
            for (int st = 0; st < 2; st++) {
                union { unsigned u[4]; short8 v; } pk;
                pk.u[0] = pku[st][0]; pk.u[1] = pku[st][1];
                pk.u[2] = pku[st][2]; pk.u[3] = pku[st][3];
                #pragma unroll
                for (int df = 0; df < 4; df++)
                    o_acc[st][df] = __builtin_amdgcn_mfma_f32_16x16x32_bf16(vf8[df], pk.v, o_acc[st][df], 0, 0, 0);
            }
        }

        if (t < nt - 1) {
            unsigned short* kn = smem + ((t + 1) & 1) * 17920;
            unsigned short* vn = kn + 128 * 72;
            #pragma unroll
            for (int rr = 0; rr < 2; ++rr) {
                *(ushort8*)&kn[(krow + rr * 64) * 72 + kcol] = kreg[rr];
                usht4 lo, hi2;
                #pragma unroll
                for (int e = 0; e < 4; e++) { lo[e] = vreg[rr][e]; hi2[e] = vreg[rr][e + 4]; }
                *(usht4*)&vn[(vrow + rr * 32) * 136 + vcol0]     = lo;
                *(usht4*)&vn[(vrow + rr * 32) * 136 + vcol0 + 8] = hi2;
            }
        }
        __syncthreads();      // single barrier per tile
    }

    // ---- combine group 1 partials into group 0 through LDS, then epilogue ----
    if (g == 1) {
        #pragma unroll
        for (int st = 0; st < 2; st++) {
            #pragma unroll
            for (int df = 0; df < 4; df++)
                *(f32x4*)&redO[(((w4 * 2 + st) * 4 + df) << 8) + lane * 4] = o_acc[st][df];
            redL[(w4 * 2 + st) * 64 + lane] = lsum[st];
        }
    }
    __syncthreads();
    if (g == 0) {
        #pragma unroll
        for (int st = 0; st < 2; st++) {
            #pragma unroll
            for (int df = 0; df < 4; df++) {
                f32x4 o1 = *(const f32x4*)&redO[(((w4 * 2 + st) * 4 + df) << 8) + lane * 4];
                o_acc[st][df] += o1;
            }
            float rs = lsum[st] + redL[(w4 * 2 + st) * 64 + lane];
            rs += __shfl_xor(rs, 16);
            rs += __shfl_xor(rs, 32);
            float inv = 1.0f / rs;
            int qg = qwbase + st * 16 + l16;
            #pragma unroll
            for (int df = 0; df < 4; df++) {
                usht4 ov;
                #pragma unroll
                for (int r = 0; r < 4; r++) ov[r] = f2bf(o_acc[st][df][r] * inv);
                *(usht4*)&ao[(size_t)(b * SEQLEN + qg) * D_MODEL + h * DKH + df * 16 + quad * 4] = ov;
            }
        }
    }
}

// ---------- kernel 3: output projection (fp32 output), 128x64 tiles, dbuf ----------
__global__ __launch_bounds__(256, 2)
void gemm_out(const unsigned short* __restrict__ AO,
              const unsigned short* __restrict__ Wo,
              float* __restrict__ out)
{
    __shared__ __align__(16) unsigned short a_lds[2 * 128 * 64];   // 32 KB
    __shared__ __align__(16) unsigned short b_lds[2 * 64 * 64];    // 16 KB

    const int m0 = blockIdx.x * 128, n0 = blockIdx.y * 64;
    f32x4 acc[4][2];
    gemm_core_128x64_db(AO, Wo, a_lds, b_lds, m0, n0, acc);

    const int lane = threadIdx.x & 63;
    const int w    = threadIdx.x >> 6;
    const int quad = lane >> 4;
    const int l16  = lane & 15;
    const int wm   = w & 1, wn = w >> 1;

    #pragma unroll
    for (int mi = 0; mi < 4; mi++)
        #pragma unroll
        for (int ni = 0; ni < 2; ni++)
            #pragma unroll
            for (int r = 0; r < 4; r++) {
                int row = m0 + wm * 64 + mi * 16 + quad * 4 + r;
                int col = n0 + wn * 32 + ni * 16 + l16;
                out[(size_t)row * D_MODEL + col] = acc[mi][ni][r];
            }
}

// ---------- launch ----------
extern "C" void kernel_launch(void* const* d_in, const int* in_sizes, int n_in,
                              void* d_out, int out_size, void* d_ws, size_t ws_size,
                              hipStream_t stream) {
    const float* X  = (const float*)d_in[0];
    const int*   pos = (const int*)d_in[1];
    const float* Wq = (const float*)d_in[2];
    const float* Wk = (const float*)d_in[3];
    const float* Wv = (const float*)d_in[4];
    const float* Wo = (const float*)d_in[5];
    float* out = (float*)d_out;

    // ws (ushorts): Xb 4M | Wqb 1M | Wkb 1M | Wvb 1M | Wob 1M | q 4M | k 4M | v^T 4M | ao 4M | tbl 512KB
    unsigned short* Xb  = (unsigned short*)d_ws;
    unsigned short* Wqb = Xb + 4194304;
    unsigned short* Wkb = Wqb + 1048576;
    unsigned short* Wvb = Wkb + 1048576;
    unsigned short* Wob = Wvb + 1048576;
    unsigned short* q_ws = Wob + 1048576;
    unsigned short* k_ws = q_ws + 4194304;
    unsigned short* v_ws = k_ws + 4194304;
    unsigned short* ao   = v_ws + 4194304;
    float2* tbl = (float2*)(ao + 4194304);

    cvt_all<<<dim3(4352), dim3(256), 0, stream>>>(X, Wq, Wk, Wv, Wo, pos,
                                                  Xb, Wqb, Wkb, Wvb, Wob, tbl);
    gemm_qkv<<<dim3(32, 8, 3), dim3(256), 0, stream>>>(Xb, Wqb, Wkb, Wvb, tbl, q_ws, k_ws, v_ws);
    attn_kernel<<<dim3(32, 16), dim3(512), 0, stream>>>(q_ws, k_ws, v_ws, ao);
    gemm_out<<<dim3(32, 16), dim3(256), 0, stream>>>(ao, Wob, out);
}

// Round 13
// 163.391 us; speedup vs baseline: 1.0278x; 1.0278x over previous
//
#include <hip/hip_runtime.h>
#include <stdint.h>

#define D_MODEL 1024
#define NH      16
#define DKH     64
#define SEQLEN  2048
#define BATCH   2
#define KDIM    1024   // inner dim of all projections

typedef __attribute__((ext_vector_type(8))) short          short8;   // 8 bf16 (4 VGPRs)
typedef __attribute__((ext_vector_type(4))) short          bf16x4;   // 4 bf16 (2 VGPRs)
typedef __attribute__((ext_vector_type(8))) unsigned short ushort8;
typedef __attribute__((ext_vector_type(4))) unsigned short usht4;    // 'ushort4' is taken by HIP
typedef __attribute__((ext_vector_type(4))) float          f32x4;

// exp2(q·k) where q pre-scaled by 0.125*log2(e) == exp(q·k/8)
#define QSCALE 0.18033688011112042f

// ---------- helpers ----------
__device__ __forceinline__ unsigned short f2bf(float f) {
    union { float f; unsigned u; } v; v.f = f;
    unsigned u = v.u;
    unsigned r = (u + 0x7FFFu + ((u >> 16) & 1u)) >> 16;   // RNE
    return (unsigned short)r;
}
__device__ __forceinline__ unsigned fbits(float f) {
    union { float f; unsigned u; } v; v.f = f; return v.u;
}

__device__ __forceinline__ void gload_lds16(const unsigned short* g, unsigned short* l) {
    __builtin_amdgcn_global_load_lds(
        (__attribute__((address_space(1))) void*)(g),
        (__attribute__((address_space(3))) void*)(l), 16, 0, 0);
}

// ---------- kernel 0: fp32 -> bf16 convert (5 tensors) + RoPE cos/sin table ----------
// COMPACT 1D grid (4352 blocks): X 2048 | Wq/Wk/Wv/Wo 512 each | tbl 256.
__global__ void cvt_all(const float* __restrict__ X,  const float* __restrict__ Wq,
                        const float* __restrict__ Wk, const float* __restrict__ Wv,
                        const float* __restrict__ Wo, const int* __restrict__ pos,
                        unsigned short* __restrict__ Xb,  unsigned short* __restrict__ Wqb,
                        unsigned short* __restrict__ Wkb, unsigned short* __restrict__ Wvb,
                        unsigned short* __restrict__ Wob, float2* __restrict__ tbl) {
    const int bid = blockIdx.x;
    if (bid >= 4096) {
        int i = (bid - 4096) * 256 + threadIdx.x;   // tbl[s][j], 2048*32 = 65536 exact
        int s = i >> 5, j = i & 31;
        float freq = expf(-((float)(2 * j) * (1.0f / 64.0f)) * 9.210340371976184f);
        float ang = (float)pos[s] * freq;
        float sn, cn;
        sincosf(ang, &sn, &cn);
        tbl[i] = make_float2(cn, sn);
        return;
    }
    const float* src; unsigned short* dst; int local;
    if (bid < 2048) { src = X; dst = Xb; local = bid; }
    else {
        int wb = bid - 2048;            // 0..2047
        int wz = wb >> 9;               // 0..3
        local  = wb & 511;
        if (wz == 0)      { src = Wq; dst = Wqb; }
        else if (wz == 1) { src = Wk; dst = Wkb; }
        else if (wz == 2) { src = Wv; dst = Wvb; }
        else              { src = Wo; dst = Wob; }
    }
    int i = (local * 256 + threadIdx.x) * 8;        // exact coverage, no bounds check
    float4 a = *(const float4*)(src + i);
    float4 b = *(const float4*)(src + i + 4);
    ushort8 o;
    o[0] = f2bf(a.x); o[1] = f2bf(a.y); o[2] = f2bf(a.z); o[3] = f2bf(a.w);
    o[4] = f2bf(b.x); o[5] = f2bf(b.y); o[6] = f2bf(b.z); o[7] = f2bf(b.w);
    *(ushort8*)(dst + i) = o;
}

// ---------- GEMM core A (qkv): C[128x128] = A * W^T, K=1024, BK=64, 16x16x32 ----------
// SINGLE-BUFFER, 2 barriers per K-step, 4 waves, 3 blocks/CU — the empirical local
// optimum for this skinny GEMM under the simple schedule. Structural variants tried
// and rejected: R4 dbuf-BK64 (lost residency), R6 8-wave (LDS-read inflation),
// R8 32x32 (wrong pipe), R10 merged-QKV (worse per-MFMA overhead + VGPR 160),
// R12 dbuf-BK32 (neutral: stage latency not the dominant term; narrower swizzle).
// XOR-swizzled staging: slot s of row r holds global k-group (s ^ (r&7)).
__device__ __forceinline__ void gemm_core_128(
    const unsigned short* __restrict__ A, const unsigned short* __restrict__ W,
    unsigned short* a_lds, unsigned short* b_lds,
    int m0, int n0, f32x4 acc[4][4])
{
    const int tid  = threadIdx.x;
    const int lane = tid & 63;
    const int w    = tid >> 6;
    const int quad = lane >> 4;
    const int l16  = lane & 15;
    const int wm   = w & 1, wn = w >> 1;

    const int row_in = lane >> 3;                 // 0..7 row within 8-row chunk
    const int cg     = ((lane & 7) ^ row_in) * 8; // xor-swizzled k-group offset (elems)

    #pragma unroll
    for (int mi = 0; mi < 4; mi++)
        #pragma unroll
        for (int ni = 0; ni < 4; ni++) {
            f32x4 z = {0.f, 0.f, 0.f, 0.f};
            acc[mi][ni] = z;
        }

    const int x7 = l16 & 7;                       // = row&7 for all frag rows

    for (int kk = 0; kk < KDIM; kk += 64) {
        __syncthreads();
        #pragma unroll
        for (int j = 0; j < 4; ++j) {
            int c = w * 4 + j;                    // chunk: 8 rows x 64 k (1KB)
            gload_lds16(A + (size_t)(m0 + c * 8 + row_in) * KDIM + kk + cg, &a_lds[c * 512]);
            gload_lds16(W + (size_t)(n0 + c * 8 + row_in) * KDIM + kk + cg, &b_lds[c * 512]);
        }
        __syncthreads();

        short8 af[2][4], bf[2][4];
        #pragma unroll
        for (int kk2 = 0; kk2 < 2; kk2++)
            #pragma unroll
            for (int i = 0; i < 4; i++) {
                int g = (kk2 * 4 + quad) ^ x7;    // de-swizzle
                af[kk2][i] = *(const short8*)&a_lds[(wm * 64 + i * 16 + l16) * 64 + g * 8];
                bf[kk2][i] = *(const short8*)&b_lds[(wn * 64 + i * 16 + l16) * 64 + g * 8];
            }
        #pragma unroll
        for (int kk2 = 0; kk2 < 2; kk2++)
            #pragma unroll
            for (int mi = 0; mi < 4; mi++)
                #pragma unroll
                for (int ni = 0; ni < 4; ni++)
                    acc[mi][ni] = __builtin_amdgcn_mfma_f32_16x16x32_bf16(af[kk2][mi], bf[kk2][ni], acc[mi][ni], 0, 0, 0);
    }
}

// ---------- GEMM core B (out): C[128x64] = A * W^T, DOUBLE-BUFFERED BK=64 ----------
// gemm_out's grid gives 2 blocks/CU (512 blocks); LDS 48KB keeps both resident.
__device__ __forceinline__ void gemm_core_128x64_db(
    const unsigned short* __restrict__ A, const unsigned short* __restrict__ W,
    unsigned short* a_lds, unsigned short* b_lds,   // a: 2*8192, b: 2*4096 ushorts
    int m0, int n0, f32x4 acc[4][2])
{
    const int tid  = threadIdx.x;
    const int lane = tid & 63;
    const int w    = tid >> 6;
    const int quad = lane >> 4;
    const int l16  = lane & 15;
    const int wm   = w & 1, wn = w >> 1;          // 2(m) x 2(n) waves, 64x32 each

    const int row_in = lane >> 3;
    const int cg     = ((lane & 7) ^ row_in) * 8;

    #pragma unroll
    for (int mi = 0; mi < 4; mi++)
        #pragma unroll
        for (int ni = 0; ni < 2; ni++) {
            f32x4 z = {0.f, 0.f, 0.f, 0.f};
            acc[mi][ni] = z;
        }

    const int x7 = l16 & 7;

    // prologue: stage k=0 into buffer 0
    #pragma unroll
    for (int j = 0; j < 4; ++j) {
        int c = w * 4 + j;                        // A: 16 chunks of 8 rows
        gload_lds16(A + (size_t)(m0 + c * 8 + row_in) * KDIM + cg, &a_lds[c * 512]);
    }
    #pragma unroll
    for (int j = 0; j < 2; ++j) {
        int c = w * 2 + j;                        // B: 8 chunks of 8 rows
        gload_lds16(W + (size_t)(n0 + c * 8 + row_in) * KDIM + cg, &b_lds[c * 512]);
    }
    __syncthreads();

    int cur = 0;
    for (int kk = 0; kk < KDIM; kk += 64) {
        if (kk + 64 < KDIM) {
            const int nxt = cur ^ 1;
            #pragma unroll
            for (int j = 0; j < 4; ++j) {
                int c = w * 4 + j;
                gload_lds16(A + (size_t)(m0 + c * 8 + row_in) * KDIM + kk + 64 + cg,
                            &a_lds[nxt * 8192 + c * 512]);
            }
            #pragma unroll
            for (int j = 0; j < 2; ++j) {
                int c = w * 2 + j;
                gload_lds16(W + (size_t)(n0 + c * 8 + row_in) * KDIM + kk + 64 + cg,
                            &b_lds[nxt * 4096 + c * 512]);
            }
        }

        const unsigned short* al = &a_lds[cur * 8192];
        const unsigned short* bl = &b_lds[cur * 4096];
        short8 af[2][4], bf[2][2];
        #pragma unroll
        for (int kk2 = 0; kk2 < 2; kk2++) {
            #pragma unroll
            for (int i = 0; i < 4; i++) {
                int g = (kk2 * 4 + quad) ^ x7;
                af[kk2][i] = *(const short8*)&al[(wm * 64 + i * 16 + l16) * 64 + g * 8];
            }
            #pragma unroll
            for (int i = 0; i < 2; i++) {
                int g = (kk2 * 4 + quad) ^ x7;
                bf[kk2][i] = *(const short8*)&bl[(wn * 32 + i * 16 + l16) * 64 + g * 8];
            }
        }
        #pragma unroll
        for (int kk2 = 0; kk2 < 2; kk2++)
            #pragma unroll
            for (int mi = 0; mi < 4; mi++)
                #pragma unroll
                for (int ni = 0; ni < 2; ni++)
                    acc[mi][ni] = __builtin_amdgcn_mfma_f32_16x16x32_bf16(af[kk2][mi], bf[kk2][ni], acc[mi][ni], 0, 0, 0);

        __syncthreads();       // vmcnt(0): next buffer landed; cur readers done
        cur ^= 1;
    }
}

// ---------- kernel 1: QKV projection + fused RoPE (Q,K) + V^T transpose-store ----------
__global__ __launch_bounds__(256, 2)
void gemm_qkv(const unsigned short* __restrict__ X,
              const unsigned short* __restrict__ Wq,
              const unsigned short* __restrict__ Wk,
              const unsigned short* __restrict__ Wv,
              const float2* __restrict__ tbl,
              unsigned short* __restrict__ q_ws,
              unsigned short* __restrict__ k_ws,
              unsigned short* __restrict__ v_ws)
{
    __shared__ __align__(16) unsigned short a_lds[128 * 64];
    __shared__ __align__(16) unsigned short b_lds[128 * 64];
    __shared__ __align__(16) unsigned short t_lds[32 * 136];   // V transpose staging

    const int z = blockIdx.z;
    const unsigned short* W = (z == 0) ? Wq : ((z == 1) ? Wk : Wv);
    const int m0 = blockIdx.x * 128, n0 = blockIdx.y * 128;

    f32x4 acc[4][4];
    gemm_core_128(X, W, a_lds, b_lds, m0, n0, acc);

    const int tid  = threadIdx.x;
    const int lane = tid & 63;
    const int w    = tid >> 6;
    const int quad = lane >> 4;
    const int l16  = lane & 15;
    const int wm   = w & 1, wn = w >> 1;

    if (z == 2) {
        // ---- V: transpose 128x128 tile through LDS, store [bh][d][s] coalesced ----
        const int bx = m0 >> 11;                 // batch
        const int c_local_w = wn * 16 + l16;     // writer column slot 0..31
        const int rd_c = tid >> 3;               // reader column slot 0..31
        const int rd_s = (tid & 7) * 16;         // reader s-offset
        #pragma unroll
        for (int ni = 0; ni < 4; ni++) {
            __syncthreads();                     // prior pass reads done
            #pragma unroll
            for (int mi = 0; mi < 4; mi++) {
                usht4 v4;
                #pragma unroll
                for (int r = 0; r < 4; r++) v4[r] = f2bf(acc[mi][ni][r]);
                *(usht4*)&t_lds[c_local_w * 136 + wm * 64 + mi * 16 + quad * 4] = v4;
            }
            __syncthreads();
            int col = n0 + (rd_c >> 4) * 64 + ni * 16 + (rd_c & 15);
            int h = col >> 6, d = col & 63;
            size_t base = (size_t)(bx * NH + h) * DKH * SEQLEN + (size_t)d * SEQLEN
                        + (m0 & 2047) + rd_s;
            ushort8 x0 = *(ushort8*)&t_lds[rd_c * 136 + rd_s];
            ushort8 x1 = *(ushort8*)&t_lds[rd_c * 136 + rd_s + 8];
            *(ushort8*)&v_ws[base]     = x0;
            *(ushort8*)&v_ws[base + 8] = x1;
        }
    } else {
        // ---- Q/K: fused RoPE on fp32 acc, then round once ----
        unsigned short* dst = (z == 0) ? q_ws : k_ws;
        const float sc = (z == 0) ? QSCALE : 1.0f;
        #pragma unroll
        for (int mi = 0; mi < 4; mi++)
            #pragma unroll
            for (int ni = 0; ni < 4; ni++)
                #pragma unroll
                for (int r = 0; r < 4; r++) {
                    int row = m0 + wm * 64 + mi * 16 + quad * 4 + r;
                    int col = n0 + wn * 64 + ni * 16 + l16;
                    int b = row >> 11, s = row & 2047;
                    int h = col >> 6,  d = col & 63;
                    float val = acc[mi][ni][r];
                    float other = __shfl_xor(val, 1);     // RoPE partner: col^1 == lane^1
                    float2 cs = tbl[s * 32 + (d >> 1)];
                    float rv = (d & 1) ? (other * cs.y + val * cs.x)
                                       : (val * cs.x - other * cs.y);
                    dst[(size_t)(b * NH + h) * SEQLEN * DKH + (size_t)s * DKH + d] =
                        f2bf(rv * sc);
                }
    }
}

// ---------- kernel 2: causal flash attention (S^T trick; 128q x 128k blocks) ----------
// grid (bh=32, y=16): qt = (y<8) ? y : 23-y -> CU-paired load balance, 2 resident
// blocks/CU. K/V LDS double-buffered (71.7 KB), ONE barrier per key-tile.
// PV uses mfma_f32_16x16x32_bf16 (K=32) via key-permuted V LDS layout (R9).
// NEW (R13, T5): s_setprio(1) around the MFMA clusters — m191 measured +4-7% on
// attn when resident waves have phase diversity (our 2 blocks/CU run different
// qt tile-counts; staging/compute skew across 8 waves). NOT applied to the GEMMs
// (m190: null-to-negative on lockstep structures).
__global__ __launch_bounds__(512, 2)
void attn_kernel(const unsigned short* __restrict__ q_ws,
                 const unsigned short* __restrict__ k_ws,
                 const unsigned short* __restrict__ v_ws,
                 unsigned short* __restrict__ ao)
{
    // per buffer: k 128*72 (18432B) + v 64*136 (17408B) = 35840B; x2 = 71680B.
    // Reduction view (aliased over buf0): redO 8192 f32 (32KB) + redL 512 f32 (2KB).
    __shared__ __align__(16) unsigned short smem[2 * 17920];
    float* redO = (float*)smem;
    float* redL = redO + 8192;

    const int bh  = blockIdx.x;
    const int y   = blockIdx.y;         // 0..15
    const int qt2 = (y < 8) ? y : (23 - y);   // CU-pairing balance map
    const int tid = threadIdx.x, lane = tid & 63, w = tid >> 6;
    const int quad = lane >> 4, l16 = lane & 15;
    const int g   = w >> 2;             // key-half group (0: keys 0-63, 1: keys 64-127)
    const int w4  = w & 3;              // query strip owner within group
    const int nf0 = g * 4;

    const size_t kqbase = (size_t)bh * SEQLEN * DKH;
    const size_t vbase  = (size_t)bh * DKH * SEQLEN;
    const int b = bh >> 4, h = bh & 15;

    // staging (512 threads, 2 chunks each)
    const int krow = tid >> 3, kcol = (tid & 7) * 8;     // K: rows krow, krow+64
    const int vrow = tid >> 4;                           // V: rows vrow, vrow+32
    const int vt   = tid & 15;                           // global key group: keys vt*8..+7
    // permuted LDS column base for keys vt*8+e: e0..3 -> +0..3, e4..7 -> +8..11
    const int vcol0 = ((vt >> 2) * 32) + ((vt & 1) * 16) + (((vt >> 1) & 1) * 4);

    const int q0  = qt2 * 128;
    const int nt  = qt2 + 1;              // # of 128-key tiles
    const int qwbase = q0 + w4 * 32;      // this wave's 32 queries

    short8 aq[2][2];
    #pragma unroll
    for (int st = 0; st < 2; st++)
        #pragma unroll
        for (int kc2 = 0; kc2 < 2; kc2++)
            aq[st][kc2] = *(const short8*)(q_ws + kqbase +
                (size_t)(qwbase + st * 16 + l16) * DKH + kc2 * 32 + quad * 8);

    f32x4 o_acc[2][4];
    #pragma unroll
    for (int st = 0; st < 2; st++)
        #pragma unroll
        for (int df = 0; df < 4; df++) { f32x4 z = {0.f,0.f,0.f,0.f}; o_acc[st][df] = z; }
    float lsum[2] = {0.f, 0.f};

    // prologue: load + stage tile 0 into buffer 0
    ushort8 kreg[2], vreg[2];
    #pragma unroll
    for (int rr = 0; rr < 2; ++rr) {
        kreg[rr] = *(const ushort8*)(k_ws + kqbase + (size_t)(krow + rr * 64) * DKH + kcol);
        vreg[rr] = *(const ushort8*)(v_ws + vbase + (size_t)(vrow + rr * 32) * SEQLEN + vt * 8);
    }
    {
        unsigned short* k0 = smem;
        unsigned short* v0 = smem + 128 * 72;
        #pragma unroll
        for (int rr = 0; rr < 2; ++rr) {
            *(ushort8*)&k0[(krow + rr * 64) * 72 + kcol] = kreg[rr];
            usht4 lo, hi2;
            #pragma unroll
            for (int e = 0; e < 4; e++) { lo[e] = vreg[rr][e]; hi2[e] = vreg[rr][e + 4]; }
            *(usht4*)&v0[(vrow + rr * 32) * 136 + vcol0]     = lo;
            *(usht4*)&v0[(vrow + rr * 32) * 136 + vcol0 + 8] = hi2;
        }
    }
    __syncthreads();

    for (int t = 0; t < nt; ++t) {
        const int s0 = t * 128;
        unsigned short* kc = smem + (t & 1) * 17920;
        unsigned short* vc = kc + 128 * 72;

        if (t < nt - 1) {
            int s1 = s0 + 128;
            #pragma unroll
            for (int rr = 0; rr < 2; ++rr) {
                kreg[rr] = *(const ushort8*)(k_ws + kqbase + (size_t)(s1 + krow + rr * 64) * DKH + kcol);
                vreg[rr] = *(const ushort8*)(v_ws + vbase + (size_t)(vrow + rr * 32) * SEQLEN + s1 + vt * 8);
            }
        }

        const bool diag = (t == nt - 1);
        #pragma unroll
        for (int np = 0; np < 2; np++) {
            unsigned pku[2][4];                 // [st][4] packed bf16 P fragments
            #pragma unroll
            for (int sub = 0; sub < 2; sub++) {
                const int nf = nf0 + np * 2 + sub;
                short8 kf0 = *(const short8*)&kc[(nf * 16 + l16) * 72 + 0 * 32 + quad * 8];
                short8 kf1 = *(const short8*)&kc[(nf * 16 + l16) * 72 + 1 * 32 + quad * 8];
                #pragma unroll
                for (int st = 0; st < 2; st++) {
                    f32x4 s = {0.f,0.f,0.f,0.f};
                    __builtin_amdgcn_s_setprio(1);                 // T5: favor MFMA wave
                    s = __builtin_amdgcn_mfma_f32_16x16x32_bf16(kf0, aq[st][0], s, 0, 0, 0);
                    s = __builtin_amdgcn_mfma_f32_16x16x32_bf16(kf1, aq[st][1], s, 0, 0, 0);
                    __builtin_amdgcn_s_setprio(0);

                    if (diag) {
                        int qg = qwbase + st * 16 + l16;
                        int kg = s0 + nf * 16 + quad * 4;
                        #pragma unroll
                        for (int r = 0; r < 4; r++)
                            s[r] = (kg + r <= qg) ? __builtin_amdgcn_exp2f(s[r]) : 0.f;
                    } else {
                        #pragma unroll
                        for (int r = 0; r < 4; r++)
                            s[r] = __builtin_amdgcn_exp2f(s[r]);
                    }
                    lsum[st] += s[0] + s[1] + s[2] + s[3];
                    pku[st][sub * 2]     = __builtin_amdgcn_perm(fbits(s[1]), fbits(s[0]), 0x07060302u);
                    pku[st][sub * 2 + 1] = __builtin_amdgcn_perm(fbits(s[3]), fbits(s[2]), 0x07060302u);
                }
            }

            // V fragments for this 32-key group (permuted layout -> contiguous b128)
            short8 vf8[4];
            #pragma unroll
            for (int df = 0; df < 4; df++)
                vf8[df] = *(const short8*)&vc[(df * 16 + l16) * 136 + (g * 2 + np) * 32 + quad * 8];

            #pragma unroll
            for (int st = 0; st < 2; st++) {
                union { unsigned u[4]; short8 v; } pk;
                pk.u[0] = pku[st][0]; pk.u[1] = pku[st][1];
                pk.u[2] = pku[st][2]; pk.u[3] = pku[st][3];
                __builtin_amdgcn_s_setprio(1);                     // T5: PV cluster
                #pragma unroll
                for (int df = 0; df < 4; df++)
                    o_acc[st][df] = __builtin_amdgcn_mfma_f32_16x16x32_bf16(vf8[df], pk.v, o_acc[st][df], 0, 0, 0);
                __builtin_amdgcn_s_setprio(0);
            }
        }

        if (t < nt - 1) {
            unsigned short* kn = smem + ((t + 1) & 1) * 17920;
            unsigned short* vn = kn + 128 * 72;
            #pragma unroll
            for (int rr = 0; rr < 2; ++rr) {
                *(ushort8*)&kn[(krow + rr * 64) * 72 + kcol] = kreg[rr];
                usht4 lo, hi2;
                #pragma unroll
                for (int e = 0; e < 4; e++) { lo[e] = vreg[rr][e]; hi2[e] = vreg[rr][e + 4]; }
                *(usht4*)&vn[(vrow + rr * 32) * 136 + vcol0]     = lo;
                *(usht4*)&vn[(vrow + rr * 32) * 136 + vcol0 + 8] = hi2;
            }
        }
        __syncthreads();      // single barrier per tile
    }

    // ---- combine group 1 partials into group 0 through LDS, then epilogue ----
    if (g == 1) {
        #pragma unroll
        for (int st = 0; st < 2; st++) {
            #pragma unroll
            for (int df = 0; df < 4; df++)
                *(f32x4*)&redO[(((w4 * 2 + st) * 4 + df) << 8) + lane * 4] = o_acc[st][df];
            redL[(w4 * 2 + st) * 64 + lane] = lsum[st];
        }
    }
    __syncthreads();
    if (g == 0) {
        #pragma unroll
        for (int st = 0; st < 2; st++) {
            #pragma unroll
            for (int df = 0; df < 4; df++) {
                f32x4 o1 = *(const f32x4*)&redO[(((w4 * 2 + st) * 4 + df) << 8) + lane * 4];
                o_acc[st][df] += o1;
            }
            float rs = lsum[st] + redL[(w4 * 2 + st) * 64 + lane];
            rs += __shfl_xor(rs, 16);
            rs += __shfl_xor(rs, 32);
            float inv = 1.0f / rs;
            int qg = qwbase + st * 16 + l16;
            #pragma unroll
            for (int df = 0; df < 4; df++) {
                usht4 ov;
                #pragma unroll
                for (int r = 0; r < 4; r++) ov[r] = f2bf(o_acc[st][df][r] * inv);
                *(usht4*)&ao[(size_t)(b * SEQLEN + qg) * D_MODEL + h * DKH + df * 16 + quad * 4] = ov;
            }
        }
    }
}

// ---------- kernel 3: output projection (fp32 output), 128x64 tiles, dbuf ----------
__global__ __launch_bounds__(256, 2)
void gemm_out(const unsigned short* __restrict__ AO,
              const unsigned short* __restrict__ Wo,
              float* __restrict__ out)
{
    __shared__ __align__(16) unsigned short a_lds[2 * 128 * 64];   // 32 KB
    __shared__ __align__(16) unsigned short b_lds[2 * 64 * 64];    // 16 KB

    const int m0 = blockIdx.x * 128, n0 = blockIdx.y * 64;
    f32x4 acc[4][2];
    gemm_core_128x64_db(AO, Wo, a_lds, b_lds, m0, n0, acc);

    const int lane = threadIdx.x & 63;
    const int w    = threadIdx.x >> 6;
    const int quad = lane >> 4;
    const int l16  = lane & 15;
    const int wm   = w & 1, wn = w >> 1;

    #pragma unroll
    for (int mi = 0; mi < 4; mi++)
        #pragma unroll
        for (int ni = 0; ni < 2; ni++)
            #pragma unroll
            for (int r = 0; r < 4; r++) {
                int row = m0 + wm * 64 + mi * 16 + quad * 4 + r;
                int col = n0 + wn * 32 + ni * 16 + l16;
                out[(size_t)row * D_MODEL + col] = acc[mi][ni][r];
            }
}

// ---------- launch ----------
extern "C" void kernel_launch(void* const* d_in, const int* in_sizes, int n_in,
                              void* d_out, int out_size, void* d_ws, size_t ws_size,
                              hipStream_t stream) {
    const float* X  = (const float*)d_in[0];
    const int*   pos = (const int*)d_in[1];
    const float* Wq = (const float*)d_in[2];
    const float* Wk = (const float*)d_in[3];
    const float* Wv = (const float*)d_in[4];
    const float* Wo = (const float*)d_in[5];
    float* out = (float*)d_out;

    // ws (ushorts): Xb 4M | Wqb 1M | Wkb 1M | Wvb 1M | Wob 1M | q 4M | k 4M | v^T 4M | ao 4M | tbl 512KB
    unsigned short* Xb  = (unsigned short*)d_ws;
    unsigned short* Wqb = Xb + 4194304;
    unsigned short* Wkb = Wqb + 1048576;
    unsigned short* Wvb = Wkb + 1048576;
    unsigned short* Wob = Wvb + 1048576;
    unsigned short* q_ws = Wob + 1048576;
    unsigned short* k_ws = q_ws + 4194304;
    unsigned short* v_ws = k_ws + 4194304;
    unsigned short* ao   = v_ws + 4194304;
    float2* tbl = (float2*)(ao + 4194304);

    cvt_all<<<dim3(4352), dim3(256), 0, stream>>>(X, Wq, Wk, Wv, Wo, pos,
                                                  Xb, Wqb, Wkb, Wvb, Wob, tbl);
    gemm_qkv<<<dim3(32, 8, 3), dim3(256), 0, stream>>>(Xb, Wqb, Wkb, Wvb, tbl, q_ws, k_ws, v_ws);
    attn_kernel<<<dim3(32, 16), dim3(512), 0, stream>>>(q_ws, k_ws, v_ws, ao);
    gemm_out<<<dim3(32, 16), dim3(256), 0, stream>>>(ao, Wob, out);
}